// Round 1
// baseline (6156.975 us; speedup 1.0000x reference)
//
#include <hip/hip_runtime.h>
#include <hip/hip_bf16.h>

#define T_STEPS 512
#define BATCH   128
#define IN      512
#define HID     512
#define KTOT    1024   // IN + HID fused
#define BT      16     // batch rows per block
#define JT      16     // hidden units per block
#define NBT     8      // BATCH / BT
#define NJT     32     // HID / JT

typedef __attribute__((ext_vector_type(8))) short bf16x8;
typedef __attribute__((ext_vector_type(4))) float f32x4;

static __device__ __forceinline__ unsigned short f2bf(float f) {
    unsigned u = __float_as_uint(f);
    unsigned r = (u + 0x7FFFu + ((u >> 16) & 1u)) >> 16;   // RNE, finite inputs only
    return (unsigned short)r;
}

// ---- prep: fuse W_ih|W_hh into bf16 [2048][1024], bias = b_ih + b_hh ----
__global__ void prep_kernel(const float* __restrict__ W_ih, const float* __restrict__ W_hh,
                            const float* __restrict__ b_ih, const float* __restrict__ b_hh,
                            unsigned short* __restrict__ Wc, float* __restrict__ bias) {
    int idx = blockIdx.x * blockDim.x + threadIdx.x;     // 0 .. 2048*1024-1
    int g = idx >> 10, k = idx & 1023;
    float v = (k < IN) ? W_ih[(size_t)g * IN + k] : W_hh[(size_t)g * HID + (k - IN)];
    Wc[idx] = f2bf(v);
    if (idx < 4 * HID) bias[idx] = b_ih[idx] + b_hh[idx];
}

// ---- persistent LSTM kernel ----
__global__ __launch_bounds__(256, 1) void lstm_kernel(
    const float* __restrict__ xin, const float* __restrict__ h0,
    const float* __restrict__ c0, const unsigned short* __restrict__ Wc,
    const float* __restrict__ bias, float* __restrict__ out,
    int* __restrict__ flags)
{
    const int tid  = threadIdx.x;
    const int bid  = blockIdx.x;
    const int bt   = bid >> 5;       // batch tile 0..7
    const int jt   = bid & 31;       // j tile 0..31
    const int wv   = tid >> 6;       // wave id = gate type (0=i,1=f,2=g,3=o)
    const int lane = tid & 63;
    const int ln15 = lane & 15;
    const int khi  = lane >> 4;

    __shared__ __align__(16) unsigned char a_lds[BT * 2048];   // [16 rows][1024 bf16], XOR-swizzled
    __shared__ float gates_s[4][BT][JT + 1];
    __shared__ float c_s[BT][JT + 1];

    // W fragments: wave wv owns gate rows wv*512 + jt*16 + (0..15), all K=1024. Held in VGPRs.
    bf16x8 wfrag[32];
    {
        const unsigned short* wrow = Wc + (size_t)(wv * HID + jt * JT + ln15) * KTOT;
        #pragma unroll
        for (int kk = 0; kk < 32; ++kk)
            wfrag[kk] = *(const bf16x8*)(wrow + kk * 32 + khi * 8);
    }
    const float biasv = bias[wv * HID + jt * JT + ln15];

    // init c tile
    {
        int b = tid >> 4, j = tid & 15;
        c_s[b][j] = c0[(size_t)(bt * BT + b) * HID + (jt * JT + j)];
    }

    const unsigned swz = (unsigned)((ln15 & 7) << 4);

    #pragma unroll 1
    for (int t = 0; t < T_STEPS; ++t) {
        // ---- wait for h_{t-1} from all 32 blocks of this batch tile ----
        if (t > 0) {
            if (tid == 0) {
                while (__hip_atomic_load(&flags[bt * T_STEPS + (t - 1)],
                                         __ATOMIC_RELAXED, __HIP_MEMORY_SCOPE_AGENT) < NJT) {
                    __builtin_amdgcn_s_sleep(1);
                }
                __builtin_amdgcn_fence(__ATOMIC_ACQUIRE, "agent");
            }
        }
        __syncthreads();   // also covers a_lds WAR + c_s init at t==0

        // ---- stage a = [x_t ; h_{t-1}] as bf16 into swizzled LDS ----
        #pragma unroll 1
        for (int row = 0; row < BT; ++row) {
            const int c4 = tid;              // float4 granule 0..255 within 1024 floats
            const int bg = bt * BT + row;
            float4 v;
            if (c4 < 128) {
                v = *(const float4*)(xin + (size_t)t * (BATCH * IN) + (size_t)bg * IN + c4 * 4);
            } else {
                const int col = (c4 - 128) * 4;
                if (t == 0) {
                    v = *(const float4*)(h0 + (size_t)bg * HID + col);
                } else {
                    const unsigned* hp = (const unsigned*)(out + (size_t)(t - 1) * (BATCH * HID)
                                                               + (size_t)bg * HID + col);
                    v.x = __uint_as_float(__hip_atomic_load(hp + 0, __ATOMIC_RELAXED, __HIP_MEMORY_SCOPE_AGENT));
                    v.y = __uint_as_float(__hip_atomic_load(hp + 1, __ATOMIC_RELAXED, __HIP_MEMORY_SCOPE_AGENT));
                    v.z = __uint_as_float(__hip_atomic_load(hp + 2, __ATOMIC_RELAXED, __HIP_MEMORY_SCOPE_AGENT));
                    v.w = __uint_as_float(__hip_atomic_load(hp + 3, __ATOMIC_RELAXED, __HIP_MEMORY_SCOPE_AGENT));
                }
            }
            ushort4 b4;
            b4.x = f2bf(v.x); b4.y = f2bf(v.y); b4.z = f2bf(v.z); b4.w = f2bf(v.w);
            unsigned off = ((unsigned)(c4 * 8)) ^ ((unsigned)((row & 7) << 4));
            *(ushort4*)(a_lds + (size_t)row * 2048 + off) = b4;
        }
        __syncthreads();

        // ---- gate GEMM: 32 MFMAs, W from registers, A from swizzled LDS ----
        f32x4 acc = {biasv, biasv, biasv, biasv};
        const unsigned char* arow = a_lds + ln15 * 2048;
        #pragma unroll
        for (int kk = 0; kk < 32; ++kk) {
            unsigned off = ((unsigned)(kk * 64 + khi * 16)) ^ swz;
            bf16x8 af = *(const bf16x8*)(arow + off);
            acc = __builtin_amdgcn_mfma_f32_16x16x32_bf16(af, wfrag[kk], acc, 0, 0, 0);
        }
        // activation (wave-uniform branch) + gate exchange
        #pragma unroll
        for (int r = 0; r < 4; ++r) {
            float xg = acc[r];
            float a = (wv == 2) ? tanhf(xg) : 1.f / (1.f + __expf(-xg));
            gates_s[wv][khi * 4 + r][ln15] = a;
        }
        __syncthreads();

        // ---- cell update: 256 threads = 16 batch x 16 j ----
        {
            int b = tid >> 4, j = tid & 15;
            float ig = gates_s[0][b][j], fg = gates_s[1][b][j];
            float gg = gates_s[2][b][j], og = gates_s[3][b][j];
            float c = fg * c_s[b][j] + ig * gg;
            float h = og * tanhf(c);
            c_s[b][j] = c;
            size_t oi = (size_t)t * (BATCH * HID) + (size_t)(bt * BT + b) * HID + (jt * JT + j);
            __hip_atomic_store((unsigned*)out + oi, __float_as_uint(h),
                               __ATOMIC_RELAXED, __HIP_MEMORY_SCOPE_AGENT);
            if (t == T_STEPS - 1) {
                size_t base = (size_t)T_STEPS * (BATCH * HID);
                size_t o2 = (size_t)(bt * BT + b) * HID + (jt * JT + j);
                out[base + o2] = h;                        // hT
                out[base + BATCH * HID + o2] = c;          // cT
            }
        }
        __syncthreads();   // drain h stores (barrier implies vmcnt(0)) before publishing

        if (tid == 0 && t < T_STEPS - 1) {
            __hip_atomic_fetch_add(&flags[bt * T_STEPS + t], 1,
                                   __ATOMIC_RELEASE, __HIP_MEMORY_SCOPE_AGENT);
        }
    }
}

extern "C" void kernel_launch(void* const* d_in, const int* in_sizes, int n_in,
                              void* d_out, int out_size, void* d_ws, size_t ws_size,
                              hipStream_t stream) {
    const float* input = (const float*)d_in[0];
    const float* h0    = (const float*)d_in[1];
    const float* c0    = (const float*)d_in[2];
    const float* W_ih  = (const float*)d_in[3];
    const float* W_hh  = (const float*)d_in[4];
    const float* b_ih  = (const float*)d_in[5];
    const float* b_hh  = (const float*)d_in[6];
    float* out = (float*)d_out;

    char* ws = (char*)d_ws;
    int*   flags = (int*)ws;                          // 8*512*4  = 16 KB
    float* bias  = (float*)(ws + 16 * 1024);          // 2048*4   = 8 KB
    unsigned short* Wc = (unsigned short*)(ws + 32 * 1024);  // 2048*1024*2 = 4 MB

    hipMemsetAsync(flags, 0, NBT * T_STEPS * sizeof(int), stream);
    prep_kernel<<<(4 * HID * KTOT) / 256, 256, 0, stream>>>(W_ih, W_hh, b_ih, b_hh, Wc, bias);
    lstm_kernel<<<NBT * NJT, 256, 0, stream>>>(input, h0, c0, Wc, bias, out, flags);
}

// Round 2
// 2908.111 us; speedup vs baseline: 2.1172x; 2.1172x over previous
//
#include <hip/hip_runtime.h>
#include <hip/hip_bf16.h>

#define T_STEPS 512
#define BATCH   128
#define IN      512
#define HID     512
#define KTOT    1024   // IN + HID fused
#define BT      16     // batch rows per block
#define JT      16     // hidden units per block
#define NBT     8      // BATCH / BT
#define NJT     32     // HID / JT

typedef __attribute__((ext_vector_type(8))) short bf16x8;
typedef __attribute__((ext_vector_type(4))) float f32x4;
typedef __attribute__((ext_vector_type(4))) unsigned int u32x4;

static __device__ __forceinline__ unsigned short f2bf(float f) {
    unsigned u = __float_as_uint(f);
    unsigned r = (u + 0x7FFFu + ((u >> 16) & 1u)) >> 16;   // RNE, finite inputs only
    return (unsigned short)r;
}

static __device__ __forceinline__ float sigmoid_fast(float x) {
    return __builtin_amdgcn_rcpf(1.f + __expf(-x));
}
static __device__ __forceinline__ float tanh_fast(float x) {
    // tanh(x) = 1 - 2/(1+e^{2x}); saturates correctly for |x| large
    return 1.f - 2.f * __builtin_amdgcn_rcpf(1.f + __expf(2.f * x));
}

// ---- prep: fuse W_ih|W_hh into bf16 [2048][1024], bias = b_ih + b_hh ----
__global__ void prep_kernel(const float* __restrict__ W_ih, const float* __restrict__ W_hh,
                            const float* __restrict__ b_ih, const float* __restrict__ b_hh,
                            unsigned short* __restrict__ Wc, float* __restrict__ bias) {
    int idx = blockIdx.x * blockDim.x + threadIdx.x;     // 0 .. 2048*1024-1
    int g = idx >> 10, k = idx & 1023;
    float v = (k < IN) ? W_ih[(size_t)g * IN + k] : W_hh[(size_t)g * HID + (k - IN)];
    Wc[idx] = f2bf(v);
    if (idx < 4 * HID) bias[idx] = b_ih[idx] + b_hh[idx];
}

// ---- persistent LSTM kernel ----
__global__ __launch_bounds__(256, 1) void lstm_kernel(
    const float* __restrict__ xin, const float* __restrict__ h0,
    const float* __restrict__ c0, const unsigned short* __restrict__ Wc,
    const float* __restrict__ bias, float* __restrict__ out,
    int* __restrict__ flags, unsigned short* __restrict__ hbuf)
{
    const int tid  = threadIdx.x;
    const int bid  = blockIdx.x;
    const int bt   = bid >> 5;       // batch tile 0..7
    const int jt   = bid & 31;       // j tile 0..31
    const int wv   = tid >> 6;       // wave id = gate type (0=i,1=f,2=g,3=o)
    const int lane = tid & 63;
    const int ln15 = lane & 15;
    const int khi  = lane >> 4;

    __shared__ __align__(16) unsigned char a_lds[BT * 2048];   // [16 rows][1024 bf16], XOR-swizzled
    __shared__ float gates_s[4][BT][JT + 1];

    // W fragments: wave wv owns gate rows wv*512 + jt*16 + (0..15), all K=1024. Held in VGPRs.
    bf16x8 wfrag[32];
    {
        const unsigned short* wrow = Wc + (size_t)(wv * HID + jt * JT + ln15) * KTOT;
        #pragma unroll
        for (int kk = 0; kk < 32; ++kk)
            wfrag[kk] = *(const bf16x8*)(wrow + kk * 32 + khi * 8);
    }
    const float biasv = bias[wv * HID + jt * JT + ln15];

    // cell state lives in a register: thread (tid>>4, tid&15) owns (b,j)
    const int cb = tid >> 4, cj = tid & 15;
    float creg = c0[(size_t)(bt * BT + cb) * HID + (jt * JT + cj)];

    const unsigned swz = (unsigned)((ln15 & 7) << 4);
    const int xrow0 = tid >> 7;          // 0..1
    const int xcol4 = tid & 127;         // float4 granule within row
    const int hrow0 = tid >> 6;          // 0..3
    const int hcol16 = tid & 63;         // 16B granule within row (bf16 path)

    // prefetch x(0) into registers
    float4 xr[8];
    #pragma unroll
    for (int i = 0; i < 8; ++i) {
        int row = xrow0 + i * 2;
        xr[i] = *(const float4*)(xin + (size_t)(bt * BT + row) * IN + xcol4 * 4);
    }

    #pragma unroll 1
    for (int t = 0; t < T_STEPS; ++t) {
        // ---- 1. write x_t (bf16) into LDS x-half ----
        #pragma unroll
        for (int i = 0; i < 8; ++i) {
            int row = xrow0 + i * 2;
            ushort4 b4;
            b4.x = f2bf(xr[i].x); b4.y = f2bf(xr[i].y);
            b4.z = f2bf(xr[i].z); b4.w = f2bf(xr[i].w);
            unsigned off = ((unsigned)(xcol4 * 8)) ^ ((unsigned)((row & 7) << 4));
            *(ushort4*)(a_lds + (size_t)row * 2048 + off) = b4;
        }
        __syncthreads();

        // ---- 2. x-half MFMAs (independent of h_{t-1}) ----
        f32x4 acc0 = {biasv, biasv, biasv, biasv};
        f32x4 acc1 = {0.f, 0.f, 0.f, 0.f};
        const unsigned char* arow = a_lds + ln15 * 2048;
        #pragma unroll
        for (int kk = 0; kk < 16; ++kk) {
            unsigned off = ((unsigned)(kk * 64 + khi * 16)) ^ swz;
            bf16x8 af = *(const bf16x8*)(arow + off);
            if (kk & 1) acc1 = __builtin_amdgcn_mfma_f32_16x16x32_bf16(af, wfrag[kk], acc1, 0, 0, 0);
            else        acc0 = __builtin_amdgcn_mfma_f32_16x16x32_bf16(af, wfrag[kk], acc0, 0, 0, 0);
        }

        // ---- 3. prefetch x(t+1) (overlaps the spin + h load + MFMA) ----
        {
            int tn = (t + 1) & (T_STEPS - 1);   // wrap at end, address always valid
            #pragma unroll
            for (int i = 0; i < 8; ++i) {
                int row = xrow0 + i * 2;
                xr[i] = *(const float4*)(xin + (size_t)tn * (BATCH * IN)
                                             + (size_t)(bt * BT + row) * IN + xcol4 * 4);
            }
        }

        // ---- 4. wait for h_{t-1} publication ----
        if (t > 0 && tid == 0) {
            while (__hip_atomic_load(&flags[bt * T_STEPS + (t - 1)],
                                     __ATOMIC_RELAXED, __HIP_MEMORY_SCOPE_AGENT) < NJT) {
                __builtin_amdgcn_s_sleep(1);
            }
        }
        __syncthreads();

        // ---- 5. stage h_{t-1} (bf16) into LDS h-half ----
        if (t == 0) {
            #pragma unroll
            for (int i = 0; i < 8; ++i) {
                int row = xrow0 + i * 2;
                float4 v = *(const float4*)(h0 + (size_t)(bt * BT + row) * HID + xcol4 * 4);
                ushort4 b4;
                b4.x = f2bf(v.x); b4.y = f2bf(v.y); b4.z = f2bf(v.z); b4.w = f2bf(v.w);
                unsigned off = ((unsigned)(xcol4 * 8)) ^ ((unsigned)((row & 7) << 4));
                *(ushort4*)(a_lds + (size_t)row * 2048 + 1024 + off) = b4;
            }
        } else {
            const unsigned short* hb = hbuf + (size_t)((t - 1) & 1) * (BATCH * HID);
            const unsigned short* p0 = hb + (size_t)(bt * BT + hrow0 +  0) * HID + hcol16 * 8;
            const unsigned short* p1 = hb + (size_t)(bt * BT + hrow0 +  4) * HID + hcol16 * 8;
            const unsigned short* p2 = hb + (size_t)(bt * BT + hrow0 +  8) * HID + hcol16 * 8;
            const unsigned short* p3 = hb + (size_t)(bt * BT + hrow0 + 12) * HID + hcol16 * 8;
            u32x4 hv0, hv1, hv2, hv3;
            asm volatile(
                "global_load_dwordx4 %0, %4, off sc0 sc1\n\t"
                "global_load_dwordx4 %1, %5, off sc0 sc1\n\t"
                "global_load_dwordx4 %2, %6, off sc0 sc1\n\t"
                "global_load_dwordx4 %3, %7, off sc0 sc1\n\t"
                "s_waitcnt vmcnt(0)"
                : "=&v"(hv0), "=&v"(hv1), "=&v"(hv2), "=&v"(hv3)
                : "v"(p0), "v"(p1), "v"(p2), "v"(p3)
                : "memory");
            unsigned offc = (unsigned)(hcol16 * 16);
            *(u32x4*)(a_lds + (size_t)(hrow0 +  0) * 2048 + 1024 + (offc ^ ((unsigned)(((hrow0 +  0) & 7) << 4)))) = hv0;
            *(u32x4*)(a_lds + (size_t)(hrow0 +  4) * 2048 + 1024 + (offc ^ ((unsigned)(((hrow0 +  4) & 7) << 4)))) = hv1;
            *(u32x4*)(a_lds + (size_t)(hrow0 +  8) * 2048 + 1024 + (offc ^ ((unsigned)(((hrow0 +  8) & 7) << 4)))) = hv2;
            *(u32x4*)(a_lds + (size_t)(hrow0 + 12) * 2048 + 1024 + (offc ^ ((unsigned)(((hrow0 + 12) & 7) << 4)))) = hv3;
        }
        __syncthreads();

        // ---- 6. h-half MFMAs + activations ----
        #pragma unroll
        for (int kk = 16; kk < 32; ++kk) {
            unsigned off = ((unsigned)(kk * 64 + khi * 16)) ^ swz;
            bf16x8 af = *(const bf16x8*)(arow + off);
            if (kk & 1) acc1 = __builtin_amdgcn_mfma_f32_16x16x32_bf16(af, wfrag[kk], acc1, 0, 0, 0);
            else        acc0 = __builtin_amdgcn_mfma_f32_16x16x32_bf16(af, wfrag[kk], acc0, 0, 0, 0);
        }
        f32x4 acc = acc0 + acc1;
        #pragma unroll
        for (int r = 0; r < 4; ++r) {
            float xg = acc[r];
            float a = (wv == 2) ? tanh_fast(xg) : sigmoid_fast(xg);
            gates_s[wv][khi * 4 + r][ln15] = a;
        }
        __syncthreads();

        // ---- 7. cell update + publish ----
        {
            float ig = gates_s[0][cb][cj], fg = gates_s[1][cb][cj];
            float gg = gates_s[2][cb][cj], og = gates_s[3][cb][cj];
            creg = fg * creg + ig * gg;
            float h = og * tanh_fast(creg);
            size_t oi = (size_t)t * (BATCH * HID) + (size_t)(bt * BT + cb) * HID + (jt * JT + cj);
            out[oi] = h;                                   // plain cached store (final output)
            if (t == T_STEPS - 1) {
                size_t base = (size_t)T_STEPS * (BATCH * HID);
                size_t o2 = (size_t)(bt * BT + cb) * HID + (jt * JT + cj);
                out[base + o2] = h;                        // hT
                out[base + BATCH * HID + o2] = creg;       // cT
            } else {
                float hn = __shfl_xor(h, 1);
                if (!(tid & 1)) {
                    unsigned p = (unsigned)f2bf(h) | ((unsigned)f2bf(hn) << 16);
                    unsigned short* hp = hbuf + (size_t)(t & 1) * (BATCH * HID)
                                              + (size_t)(bt * BT + cb) * HID + (jt * JT + cj);
                    asm volatile("global_store_dword %0, %1, off sc0 sc1"
                                 :: "v"(hp), "v"(p) : "memory");
                }
            }
        }
        __syncthreads();   // compiler emits vmcnt(0) before s_barrier → h stores drained

        if (tid == 0 && t < T_STEPS - 1) {
            __hip_atomic_fetch_add(&flags[bt * T_STEPS + t], 1,
                                   __ATOMIC_RELEASE, __HIP_MEMORY_SCOPE_AGENT);
        }
    }
}

extern "C" void kernel_launch(void* const* d_in, const int* in_sizes, int n_in,
                              void* d_out, int out_size, void* d_ws, size_t ws_size,
                              hipStream_t stream) {
    const float* input = (const float*)d_in[0];
    const float* h0    = (const float*)d_in[1];
    const float* c0    = (const float*)d_in[2];
    const float* W_ih  = (const float*)d_in[3];
    const float* W_hh  = (const float*)d_in[4];
    const float* b_ih  = (const float*)d_in[5];
    const float* b_hh  = (const float*)d_in[6];
    float* out = (float*)d_out;

    char* ws = (char*)d_ws;
    int*   flags = (int*)ws;                                   // 8*512*4 = 16 KB
    float* bias  = (float*)(ws + 16 * 1024);                   // 2048*4  = 8 KB
    unsigned short* hbuf = (unsigned short*)(ws + 32 * 1024);  // 2*128*512*2 = 256 KB
    unsigned short* Wc   = (unsigned short*)(ws + 32 * 1024 + 256 * 1024);  // 4 MB

    hipMemsetAsync(flags, 0, NBT * T_STEPS * sizeof(int), stream);
    prep_kernel<<<(4 * HID * KTOT) / 256, 256, 0, stream>>>(W_ih, W_hh, b_ih, b_hh, Wc, bias);
    lstm_kernel<<<NBT * NJT, 256, 0, stream>>>(input, h0, c0, Wc, bias, out, flags, hbuf);
}

// Round 3
// 1764.123 us; speedup vs baseline: 3.4901x; 1.6485x over previous
//
#include <hip/hip_runtime.h>
#include <hip/hip_bf16.h>

#define T_STEPS 512
#define BATCH   128
#define IN      512
#define HID     512
#define KTOT    1024   // IN + HID fused
#define BT      16     // batch rows per block
#define JT      16     // hidden units per block
#define NBT     8      // BATCH / BT (= batch groups, one per XCD if round-robin holds)
#define NJT     32     // HID / JT (blocks per group)

typedef __attribute__((ext_vector_type(8))) short bf16x8;
typedef __attribute__((ext_vector_type(4))) float f32x4;
typedef __attribute__((ext_vector_type(4))) unsigned int u32x4;

static __device__ __forceinline__ unsigned short f2bf(float f) {
    unsigned u = __float_as_uint(f);
    unsigned r = (u + 0x7FFFu + ((u >> 16) & 1u)) >> 16;   // RNE, finite inputs only
    return (unsigned short)r;
}

static __device__ __forceinline__ float sigmoid_fast(float x) {
    return __builtin_amdgcn_rcpf(1.f + __expf(-x));
}
static __device__ __forceinline__ float tanh_fast(float x) {
    return 1.f - 2.f * __builtin_amdgcn_rcpf(1.f + __expf(2.f * x));
}

// ---- prep: fuse W_ih|W_hh into bf16 [2048][1024], bias = b_ih + b_hh ----
__global__ void prep_kernel(const float* __restrict__ W_ih, const float* __restrict__ W_hh,
                            const float* __restrict__ b_ih, const float* __restrict__ b_hh,
                            unsigned short* __restrict__ Wc, float* __restrict__ bias) {
    int idx = blockIdx.x * blockDim.x + threadIdx.x;     // 0 .. 2048*1024-1
    int g = idx >> 10, k = idx & 1023;
    float v = (k < IN) ? W_ih[(size_t)g * IN + k] : W_hh[(size_t)g * HID + (k - IN)];
    Wc[idx] = f2bf(v);
    if (idx < 4 * HID) bias[idx] = b_ih[idx] + b_hh[idx];
}

// ---- persistent LSTM kernel ----
__global__ __launch_bounds__(256, 1) void lstm_kernel(
    const float* __restrict__ xin, const float* __restrict__ h0,
    const float* __restrict__ c0, const unsigned short* __restrict__ Wc,
    const float* __restrict__ bias, float* __restrict__ out,
    int* __restrict__ flags, int* __restrict__ test,
    int* __restrict__ acnt, int* __restrict__ aok,
    unsigned short* __restrict__ hbuf)
{
    const int tid  = threadIdx.x;
    const int bid  = blockIdx.x;
    const int bt   = bid & 7;        // batch group (presumed XCD id via round-robin)
    const int jt   = bid >> 3;       // j tile 0..31
    const int wv   = tid >> 6;       // wave id = gate type (0=i,1=f,2=g,3=o)
    const int lane = tid & 63;
    const int ln15 = lane & 15;
    const int khi  = lane >> 4;

    __shared__ __align__(16) unsigned char a_lds[BT * 2048];   // [16 rows][1024 bf16], XOR-swizzled
    __shared__ float gates_s[4][BT][18];
    __shared__ int fast_s;

    // W fragments: wave wv owns gate rows wv*512 + jt*16 + (0..15), all K=1024. Held in VGPRs.
    bf16x8 wfrag[32];
    {
        const unsigned short* wrow = Wc + (size_t)(wv * HID + jt * JT + ln15) * KTOT;
        #pragma unroll
        for (int kk = 0; kk < 32; ++kk)
            wfrag[kk] = *(const bf16x8*)(wrow + kk * 32 + khi * 8);
    }
    const float biasv = bias[wv * HID + jt * JT + ln15];

    const int cb = tid >> 4, cj = tid & 15;
    float creg = c0[(size_t)(bt * BT + cb) * HID + (jt * JT + cj)];

    const unsigned swz = (unsigned)((ln15 & 7) << 4);
    const int xrow0 = tid >> 7;          // 0..1
    const int xcol4 = tid & 127;         // float4 granule within row
    const int hrow0 = wv;                // wave writes h rows {wv, wv+4, wv+8, wv+12}
    const int hcol16 = tid & 63;         // 16B granule within row

    // prefetch x(0)
    float4 xr[8];
    #pragma unroll
    for (int i = 0; i < 8; ++i)
        xr[i] = *(const float4*)(xin + (size_t)(bt * BT + xrow0 + 2 * i) * IN + xcol4 * 4);

    // ---- startup: empirical same-L2 coherence probe (bounded; airtight fallback) ----
    {
        if (tid == 0) {
            int* tp = test + bt * 32 + jt;
            int tok = 0x5EED;
            asm volatile("global_store_dword %0, %1, off sc0" :: "v"(tp), "v"(tok) : "memory");
        }
        if (tid < 64) {
            const int* tp = test + bt * 32 + (lane & 31);
            bool ok = false;
            for (int it = 0; it < 4096 && !ok; ++it) {
                int v;
                asm volatile("global_load_dword %0, %1, off sc0\n\ts_waitcnt vmcnt(0)"
                             : "=v"(v) : "v"(tp) : "memory");
                ok = (__ballot(v == 0x5EED) == ~0ull);
            }
            if (tid == 0) {
                __hip_atomic_fetch_add(&aok[bt], ok ? 1 : 0, __ATOMIC_RELEASE, __HIP_MEMORY_SCOPE_AGENT);
                __hip_atomic_fetch_add(&acnt[bt], 1, __ATOMIC_RELEASE, __HIP_MEMORY_SCOPE_AGENT);
                while (__hip_atomic_load(&acnt[bt], __ATOMIC_ACQUIRE, __HIP_MEMORY_SCOPE_AGENT) < NJT)
                    __builtin_amdgcn_s_sleep(8);
                fast_s = (__hip_atomic_load(&aok[bt], __ATOMIC_RELAXED, __HIP_MEMORY_SCOPE_AGENT) == NJT);
            }
        }
        __syncthreads();
    }
    const bool fast = (fast_s != 0);

    #pragma unroll 1
    for (int t = 0; t < T_STEPS; ++t) {
        // ---- P1: write x_t (bf16) into LDS x-half ----
        #pragma unroll
        for (int i = 0; i < 8; ++i) {
            int row = xrow0 + 2 * i;
            ushort4 b4;
            b4.x = f2bf(xr[i].x); b4.y = f2bf(xr[i].y);
            b4.z = f2bf(xr[i].z); b4.w = f2bf(xr[i].w);
            unsigned off = ((unsigned)(xcol4 * 8)) ^ ((unsigned)((row & 7) << 4));
            *(ushort4*)(a_lds + (size_t)row * 2048 + off) = b4;
        }
        __syncthreads();   // A

        // ---- P2: x-half MFMAs ----
        f32x4 acc0 = {biasv, biasv, biasv, biasv};
        f32x4 acc1 = {0.f, 0.f, 0.f, 0.f};
        const unsigned char* arow = a_lds + ln15 * 2048;
        #pragma unroll
        for (int kk = 0; kk < 16; ++kk) {
            unsigned off = ((unsigned)(kk * 64 + khi * 16)) ^ swz;
            bf16x8 af = *(const bf16x8*)(arow + off);
            if (kk & 1) acc1 = __builtin_amdgcn_mfma_f32_16x16x32_bf16(af, wfrag[kk], acc1, 0, 0, 0);
            else        acc0 = __builtin_amdgcn_mfma_f32_16x16x32_bf16(af, wfrag[kk], acc0, 0, 0, 0);
        }

        // ---- P3: poll per-producer flags (all waves, 32 lanes each) ----
        if (t > 0) {
            const int* fp = flags + bt * 32 + (lane & 31);
            for (;;) {
                int v;
                if (fast) asm volatile("global_load_dword %0, %1, off sc0\n\ts_waitcnt vmcnt(0)"
                                       : "=v"(v) : "v"(fp) : "memory");
                else      asm volatile("global_load_dword %0, %1, off sc0 sc1\n\ts_waitcnt vmcnt(0)"
                                       : "=v"(v) : "v"(fp) : "memory");
                if (__ballot(v >= t) == ~0ull) break;
            }
        }

        // ---- P4: stage h_{t-1} (bf16) into LDS h-half ----
        if (t == 0) {
            #pragma unroll
            for (int i = 0; i < 8; ++i) {
                int row = xrow0 + 2 * i;
                float4 v = *(const float4*)(h0 + (size_t)(bt * BT + row) * HID + xcol4 * 4);
                ushort4 b4;
                b4.x = f2bf(v.x); b4.y = f2bf(v.y); b4.z = f2bf(v.z); b4.w = f2bf(v.w);
                unsigned off = ((unsigned)(xcol4 * 8)) ^ ((unsigned)((row & 7) << 4));
                *(ushort4*)(a_lds + (size_t)row * 2048 + 1024 + off) = b4;
            }
        } else {
            const unsigned short* hb = hbuf + (size_t)((t - 1) & 1) * (BATCH * HID);
            const unsigned short* p0 = hb + (size_t)(bt * BT + hrow0 +  0) * HID + hcol16 * 8;
            const unsigned short* p1 = hb + (size_t)(bt * BT + hrow0 +  4) * HID + hcol16 * 8;
            const unsigned short* p2 = hb + (size_t)(bt * BT + hrow0 +  8) * HID + hcol16 * 8;
            const unsigned short* p3 = hb + (size_t)(bt * BT + hrow0 + 12) * HID + hcol16 * 8;
            u32x4 hv0, hv1, hv2, hv3;
            if (fast) {
                asm volatile(
                    "global_load_dwordx4 %0, %4, off sc0\n\t"
                    "global_load_dwordx4 %1, %5, off sc0\n\t"
                    "global_load_dwordx4 %2, %6, off sc0\n\t"
                    "global_load_dwordx4 %3, %7, off sc0\n\t"
                    "s_waitcnt vmcnt(0)"
                    : "=&v"(hv0), "=&v"(hv1), "=&v"(hv2), "=&v"(hv3)
                    : "v"(p0), "v"(p1), "v"(p2), "v"(p3) : "memory");
            } else {
                asm volatile(
                    "global_load_dwordx4 %0, %4, off sc0 sc1\n\t"
                    "global_load_dwordx4 %1, %5, off sc0 sc1\n\t"
                    "global_load_dwordx4 %2, %6, off sc0 sc1\n\t"
                    "global_load_dwordx4 %3, %7, off sc0 sc1\n\t"
                    "s_waitcnt vmcnt(0)"
                    : "=&v"(hv0), "=&v"(hv1), "=&v"(hv2), "=&v"(hv3)
                    : "v"(p0), "v"(p1), "v"(p2), "v"(p3) : "memory");
            }
            unsigned offc = (unsigned)(hcol16 * 16);
            *(u32x4*)(a_lds + (size_t)(hrow0 +  0) * 2048 + 1024 + (offc ^ ((unsigned)(((hrow0 +  0) & 7) << 4)))) = hv0;
            *(u32x4*)(a_lds + (size_t)(hrow0 +  4) * 2048 + 1024 + (offc ^ ((unsigned)(((hrow0 +  4) & 7) << 4)))) = hv1;
            *(u32x4*)(a_lds + (size_t)(hrow0 +  8) * 2048 + 1024 + (offc ^ ((unsigned)(((hrow0 +  8) & 7) << 4)))) = hv2;
            *(u32x4*)(a_lds + (size_t)(hrow0 + 12) * 2048 + 1024 + (offc ^ ((unsigned)(((hrow0 + 12) & 7) << 4)))) = hv3;
        }
        __syncthreads();   // B

        // ---- P5: h-half MFMAs + activations + gate exchange ----
        #pragma unroll
        for (int kk = 16; kk < 32; ++kk) {
            unsigned off = ((unsigned)(kk * 64 + khi * 16)) ^ swz;
            bf16x8 af = *(const bf16x8*)(arow + off);
            if (kk & 1) acc1 = __builtin_amdgcn_mfma_f32_16x16x32_bf16(af, wfrag[kk], acc1, 0, 0, 0);
            else        acc0 = __builtin_amdgcn_mfma_f32_16x16x32_bf16(af, wfrag[kk], acc0, 0, 0, 0);
        }
        f32x4 acc = acc0 + acc1;
        #pragma unroll
        for (int r = 0; r < 4; ++r) {
            float xg = acc[r];
            float a = (wv == 2) ? tanh_fast(xg) : sigmoid_fast(xg);
            gates_s[wv][khi * 4 + r][ln15] = a;
        }
        __syncthreads();   // C

        // ---- P6/P7: cell update + h publish ----
        float ig = gates_s[0][cb][cj], fg = gates_s[1][cb][cj];
        float gg = gates_s[2][cb][cj], og = gates_s[3][cb][cj];
        creg = fg * creg + ig * gg;
        float h = og * tanh_fast(creg);
        float hn = __shfl_xor(h, 1);
        if (t < T_STEPS - 1 && !(tid & 1)) {
            unsigned p = (unsigned)f2bf(h) | ((unsigned)f2bf(hn) << 16);
            unsigned short* hp = hbuf + (size_t)(t & 1) * (BATCH * HID)
                                      + (size_t)(bt * BT + cb) * HID + (jt * JT + cj);
            if (fast) asm volatile("global_store_dword %0, %1, off sc0"     :: "v"(hp), "v"(p) : "memory");
            else      asm volatile("global_store_dword %0, %1, off sc0 sc1" :: "v"(hp), "v"(p) : "memory");
        }
        __syncthreads();   // D — vmcnt(0) drains only hbuf stores (out/x issued after)

        // ---- P8: flag publish ----
        if (tid == 0 && t < T_STEPS - 1) {
            int* fp = flags + bt * 32 + jt;
            int val = t + 1;
            if (fast) asm volatile("global_store_dword %0, %1, off sc0"     :: "v"(fp), "v"(val) : "memory");
            else      asm volatile("global_store_dword %0, %1, off sc0 sc1" :: "v"(fp), "v"(val) : "memory");
        }

        // ---- P9: off-chain work: out store, hT/cT, prefetch x(t+1) ----
        {
            size_t oi = (size_t)t * (BATCH * HID) + (size_t)(bt * BT + cb) * HID + (jt * JT + cj);
            out[oi] = h;
            if (t == T_STEPS - 1) {
                size_t base = (size_t)T_STEPS * (BATCH * HID);
                size_t o2 = (size_t)(bt * BT + cb) * HID + (jt * JT + cj);
                out[base + o2] = h;
                out[base + BATCH * HID + o2] = creg;
            }
            int tn = (t + 1) & (T_STEPS - 1);
            #pragma unroll
            for (int i = 0; i < 8; ++i)
                xr[i] = *(const float4*)(xin + (size_t)tn * (BATCH * IN)
                                             + (size_t)(bt * BT + xrow0 + 2 * i) * IN + xcol4 * 4);
        }
    }
}

extern "C" void kernel_launch(void* const* d_in, const int* in_sizes, int n_in,
                              void* d_out, int out_size, void* d_ws, size_t ws_size,
                              hipStream_t stream) {
    const float* input = (const float*)d_in[0];
    const float* h0    = (const float*)d_in[1];
    const float* c0    = (const float*)d_in[2];
    const float* W_ih  = (const float*)d_in[3];
    const float* W_hh  = (const float*)d_in[4];
    const float* b_ih  = (const float*)d_in[5];
    const float* b_hh  = (const float*)d_in[6];
    float* out = (float*)d_out;

    char* ws = (char*)d_ws;
    int*   flags = (int*)(ws + 0);          // 8*32*4 = 1 KB
    int*   test  = (int*)(ws + 1024);       // 8*32*4 = 1 KB
    int*   acnt  = (int*)(ws + 2048);       // 8*4
    int*   aok   = (int*)(ws + 2080);       // 8*4
    float* bias  = (float*)(ws + 4096);                        // 8 KB
    unsigned short* hbuf = (unsigned short*)(ws + 12288);      // 2*128*512*2 = 256 KB
    unsigned short* Wc   = (unsigned short*)(ws + 12288 + 262144);  // 4 MB

    hipMemsetAsync(ws, 0, 4096, stream);    // flags + test + acnt + aok
    prep_kernel<<<(4 * HID * KTOT) / 256, 256, 0, stream>>>(W_ih, W_hh, b_ih, b_hh, Wc, bias);
    lstm_kernel<<<NBT * NJT, 256, 0, stream>>>(input, h0, c0, Wc, bias, out,
                                               flags, test, acnt, aok, hbuf);
}